// Round 6
// baseline (1595.994 us; speedup 1.0000x reference)
//
#include <hip/hip_runtime.h>
#include <hip/hip_bf16.h>
#include <math.h>

typedef __hip_bfloat16 bf16;
typedef __attribute__((ext_vector_type(8))) short short8;   // 8 x bf16 MFMA frag
typedef __attribute__((ext_vector_type(4))) float floatx4;  // 4 x f32 MFMA acc

// Problem constants: B=64, DIM=256, HID=512, NH=4, KD=16, D=64, 28x28, WH=7
#define BB    64
#define DIMC  256
#define HIDC  512
#define NHH   4
#define HH_   28
#define WW_   28
#define PP    784   // 28*28

__device__ __forceinline__ float toF(float x) { return x; }
__device__ __forceinline__ float toF(bf16 x) { return __bfloat162float(x); }
__device__ __forceinline__ void stV(float* p, float v) { *p = v; }
__device__ __forceinline__ void stV(bf16* p, float v) { *p = __float2bfloat16(v); }

__device__ __forceinline__ unsigned short f2bits(float f) {
    union { bf16 h; unsigned short u; } cv; cv.h = __float2bfloat16(f); return cv.u;
}
__device__ __forceinline__ float bits2f(unsigned short u) {
    union { unsigned int u32; float f; } cv; cv.u32 = ((unsigned int)u) << 16; return cv.f;
}
__device__ __forceinline__ unsigned short ldbits(const float* p) { return f2bits(*p); }
__device__ __forceinline__ unsigned short ldbits(const bf16* p) {
    return *(const unsigned short*)p;
}

// ---------------------------------------------------------------------------
// fp32 -> bf16 weight convert
// ---------------------------------------------------------------------------
__global__ __launch_bounds__(256) void cvt_f2b(
    const float* __restrict__ s, bf16* __restrict__ d, int n)
{
    int i = blockIdx.x * 256 + threadIdx.x;
    if (i < n) d[i] = __float2bfloat16(s[i]);
}

// ---------------------------------------------------------------------------
// Depthwise 3x3 conv + BN + residual (NCHW) — proven (round 3)
// ---------------------------------------------------------------------------
__global__ __launch_bounds__(256) void dw3x3_kernel(
    const float* __restrict__ in, const float* __restrict__ w,
    const float* __restrict__ s, const float* __restrict__ b,
    float* __restrict__ out)
{
    int nc = blockIdx.x;
    int c  = nc & (DIMC - 1);
    const float* ip = in + (size_t)nc * PP;
    float*       op = out + (size_t)nc * PP;
    float w9[9];
#pragma unroll
    for (int i = 0; i < 9; i++) w9[i] = w[c * 9 + i];
    float sc = s[c], bb = b[c];
    for (int p = threadIdx.x; p < PP; p += 256) {
        int h = p / WW_, x = p % WW_;
        float acc = 0.f;
#pragma unroll
        for (int i = 0; i < 3; i++) {
            int hh = h + i - 1;
            if (hh < 0 || hh >= HH_) continue;
#pragma unroll
            for (int j = 0; j < 3; j++) {
                int xx = x + j - 1;
                if (xx < 0 || xx >= WW_) continue;
                acc += w9[i * 3 + j] * ip[hh * WW_ + xx];
            }
        }
        op[p] = ip[p] + acc * sc + bb;
    }
}

// ---------------------------------------------------------------------------
// Per-head depthwise 5x5 + BN on q channels of bf16 QKV (NCHW)
// ---------------------------------------------------------------------------
__global__ __launch_bounds__(256) void dws5x5_kernel(
    const bf16* __restrict__ qkv, const float* __restrict__ w,
    const float* __restrict__ s, const float* __restrict__ b,
    float* __restrict__ qout)
{
    int blk = blockIdx.x;         // n*64 + hh*16 + kc
    int n = blk >> 6, hk = blk & 63;
    int hh = hk >> 4, kc = hk & 15;
    const bf16* ip = qkv + ((size_t)n * 384 + hh * 96 + kc) * PP;
    float*      op = qout + (size_t)blk * PP;
    float w25[25];
#pragma unroll
    for (int i = 0; i < 25; i++) w25[i] = w[hk * 25 + i];
    float sc = s[hk], bb = b[hk];
    for (int p = threadIdx.x; p < PP; p += 256) {
        int h = p / WW_, x = p % WW_;
        float acc = 0.f;
#pragma unroll
        for (int i = 0; i < 5; i++) {
            int h2 = p / WW_ + i - 2;
            if (h2 < 0 || h2 >= HH_) continue;
#pragma unroll
            for (int j = 0; j < 5; j++) {
                int x2 = x + j - 2;
                if (x2 < 0 || x2 >= WW_) continue;
                acc += w25[i * 5 + j] * toF(ip[h2 * WW_ + x2]);
            }
        }
        op[p] = acc * sc + bb;
    }
}

// ---------------------------------------------------------------------------
// 1x1 conv as bf16 MFMA GEMM (NCHW):  out[n,co,p] = sum_ci W[co,ci]*X[n,ci,p]
// Tile 64(co) x 112(p) (784 = 7*112, zero waste), K-step 32, 4 waves.
// Staging: thread handles (pp, G): loads 8 consecutive k-rows at one p
// (8 coalesced scalar loads), writes ONE ds_write_b128 at Blds[pp*40+G*8]
// -> start banks (20*pp)%32 tile all 32 banks: conflict-free.
// Read path identical to proven r5: B[k=quad*8+j][p=row], b128 at row*40+quad*8.
// grid (7, M/64, 64)
// ---------------------------------------------------------------------------
template <typename Tin, typename Tout, bool RELU, bool RES>
__global__ __launch_bounds__(256) void gemm_mfma(
    const bf16* __restrict__ Wb,    // [M][K] bf16
    const Tin*  __restrict__ X,     // [64][K][784]
    const float* __restrict__ S, const float* __restrict__ Bb,
    const float* __restrict__ res,  // [64][M][784] fp32 (if RES)
    Tout* __restrict__ out,         // [64][M][784]
    int M, int K)
{
    int n    = blockIdx.z;
    int co0  = blockIdx.y * 64;
    int p0   = blockIdx.x * 112;
    int tid  = threadIdx.x;
    int wv   = tid >> 6;
    int ln   = tid & 63;
    int l15  = ln & 15;
    int quad = ln >> 4;

    __shared__ __align__(16) unsigned short Blds[112 * 40];  // [pp][kk], pitch 40

    floatx4 acc[7];
#pragma unroll
    for (int t = 0; t < 7; t++) acc[t] = (floatx4){0.f, 0.f, 0.f, 0.f};

    const bf16* Arow = Wb + (size_t)(co0 + wv * 16 + l15) * K + quad * 8;
    const Tin*  Xn   = X + (size_t)n * K * PP;

    // staging task split: 448 = 112 pp x 4 granules; tid does idx and idx+256
    int pp_a = tid % 112, G_a = tid / 112;          // always < 448
    int idx_b = tid + 256;
    int pp_b = idx_b % 112, G_b = idx_b / 112;      // valid if idx_b < 448

    for (int k0 = 0; k0 < K; k0 += 32) {
        {
            const Tin* src = Xn + (size_t)(k0 + G_a * 8) * PP + p0 + pp_a;
            union { unsigned short v[8]; uint4 q; } pk;
#pragma unroll
            for (int j = 0; j < 8; j++) pk.v[j] = ldbits(src + (size_t)j * PP);
            *(uint4*)&Blds[pp_a * 40 + G_a * 8] = pk.q;
        }
        if (idx_b < 448) {
            const Tin* src = Xn + (size_t)(k0 + G_b * 8) * PP + p0 + pp_b;
            union { unsigned short v[8]; uint4 q; } pk;
#pragma unroll
            for (int j = 0; j < 8; j++) pk.v[j] = ldbits(src + (size_t)j * PP);
            *(uint4*)&Blds[pp_b * 40 + G_b * 8] = pk.q;
        }
        short8 afrag = *(const short8*)(Arow + k0);
        __syncthreads();
#pragma unroll
        for (int t = 0; t < 7; t++) {
            short8 bfrag = *(const short8*)&Blds[(t * 16 + l15) * 40 + quad * 8];
            acc[t] = __builtin_amdgcn_mfma_f32_16x16x32_bf16(afrag, bfrag, acc[t], 0, 0, 0);
        }
        __syncthreads();
    }

    int cobase = co0 + wv * 16 + quad * 4;
    float s4[4], b4[4];
#pragma unroll
    for (int r = 0; r < 4; r++) { s4[r] = S[cobase + r]; b4[r] = Bb[cobase + r]; }

#pragma unroll
    for (int t = 0; t < 7; t++) {
        int p = p0 + t * 16 + l15;   // always < 784
#pragma unroll
        for (int r = 0; r < 4; r++) {
            float y = acc[t][r] * s4[r] + b4[r];
            if (RELU) y = fmaxf(y, 0.f);
            size_t o = ((size_t)n * M + cobase + r) * PP + p;
            if (RES) y += res[o];
            stV(&out[o], y);
        }
    }
}

// ---------------------------------------------------------------------------
// 7x7 window attention, rewritten for coalesced access.
// Block per (n, head, window-row, window-col-pair): grid (8, 4, 64).
// Covers 2 adjacent windows: rows h0..h0+6, cols col0..col0+13 (lp = r*14+c).
// q/k/v staged bf16 in LDS (conflict-free pitches), S fp32 pitch 51.
// O = relu(attn@V) stashed via LDS (reusing V buffer) for coalesced writes.
// ---------------------------------------------------------------------------
__global__ __launch_bounds__(256) void attn_kernel(
    const float* __restrict__ Q,       // [64][64][784] fp32  (hk = hh*16+kc)
    const bf16*  __restrict__ KV,      // [64][384][784] bf16 (c = hh*96 + ...)
    const float* __restrict__ pos,     // [4][49][49]
    bf16* __restrict__ O)              // [64][256][784] bf16 (c = hh*64+d)
{
    int wjp = blockIdx.x & 1, wi = blockIdx.x >> 1;
    int hh  = blockIdx.y, n = blockIdx.z;
    int tid = threadIdx.x;
    int pbase = wi * 7 * 28 + wjp * 14;   // global p = pbase + r*28 + c

    __shared__ unsigned short qL[16 * 98];   // [kc][lp]
    __shared__ unsigned short kL[16 * 98];
    __shared__ unsigned short vL[98 * 66];   // [lp][d] pitch 66 (bank step 1)
    __shared__ float          sL[98 * 51];   // [w*49+qi][ki] pitch 51 (gcd(51,32)=1)

    const unsigned short* KVu = (const unsigned short*)KV;

    // ---- load q, k (16 ch x 98 pos, contiguous 14-elem runs) ----
    for (int idx = tid; idx < 1568; idx += 256) {
        int kc = idx / 98, lp = idx % 98;
        int p  = pbase + (lp / 14) * 28 + lp % 14;
        qL[kc * 98 + lp] = f2bits(Q[((size_t)(n * 64 + hh * 16 + kc)) * PP + p]);
        kL[kc * 98 + lp] = KVu[((size_t)(n * 384 + hh * 96 + 16 + kc)) * PP + p];
    }
    // ---- load v (64 ch x 98 pos) ----
    for (int idx = tid; idx < 6272; idx += 256) {
        int d = idx / 98, lp = idx % 98;
        int p = pbase + (lp / 14) * 28 + lp % 14;
        vL[lp * 66 + d] = KVu[((size_t)(n * 384 + hh * 96 + 32 + d)) * PP + p];
    }
    __syncthreads();

    // ---- S = 0.25*q.k + pos  (2 windows x 49 x 49) ----
    for (int idx = tid; idx < 4802; idx += 256) {
        int w  = idx / 2401;
        int rm = idx - w * 2401;
        int qi = rm / 49, ki = rm - qi * 49;
        int lpq = (qi / 7) * 14 + w * 7 + qi % 7;
        int lpk = (ki / 7) * 14 + w * 7 + ki % 7;
        float acc = 0.f;
#pragma unroll
        for (int kc = 0; kc < 16; kc++)
            acc += bits2f(qL[kc * 98 + lpq]) * bits2f(kL[kc * 98 + lpk]);
        sL[(w * 49 + qi) * 51 + ki] = acc * 0.25f + pos[(hh * 49 + qi) * 49 + ki];
    }
    __syncthreads();

    // ---- softmax (one thread per row; 98 rows) ----
    if (tid < 98) {
        float* row = &sL[tid * 51];
        float m = row[0];
        for (int ki = 1; ki < 49; ki++) m = fmaxf(m, row[ki]);
        float sum = 0.f;
        for (int ki = 0; ki < 49; ki++) {
            float e = __expf(row[ki] - m);
            row[ki] = e;
            sum += e;
        }
        float inv = 1.f / sum;
        for (int ki = 0; ki < 49; ki++) row[ki] *= inv;
    }
    __syncthreads();

    // ---- O = relu(attn @ V): thread owns channel d, rows rr,rr+4,... ----
    int d = tid & 63, rr = tid >> 6;
    float ores[2][13];
#pragma unroll
    for (int w = 0; w < 2; w++) {
        float vreg[49];
#pragma unroll
        for (int ki = 0; ki < 49; ki++) {
            int lp = (ki / 7) * 14 + w * 7 + ki % 7;
            vreg[ki] = bits2f(vL[lp * 66 + d]);
        }
#pragma unroll
        for (int j = 0; j < 13; j++) {
            int qi = rr + j * 4;
            if (qi < 49) {
                const float* srow = &sL[(w * 49 + qi) * 51];
                float acc = 0.f;
#pragma unroll
                for (int ki = 0; ki < 49; ki++) acc += srow[ki] * vreg[ki];
                ores[w][j] = fmaxf(acc, 0.f);
            }
        }
    }
    __syncthreads();   // all reads of vL complete

    // stash O into vL as [lp][d] for coalesced global writes
#pragma unroll
    for (int w = 0; w < 2; w++)
#pragma unroll
        for (int j = 0; j < 13; j++) {
            int qi = rr + j * 4;
            if (qi < 49) {
                int lp = (qi / 7) * 14 + w * 7 + qi % 7;
                vL[lp * 66 + d] = f2bits(ores[w][j]);
            }
        }
    __syncthreads();

    unsigned short* Ou = (unsigned short*)O;
    for (int idx = tid; idx < 6272; idx += 256) {
        int dd = idx / 98, lp = idx % 98;
        int p  = pbase + (lp / 14) * 28 + lp % 14;
        Ou[((size_t)(n * 256 + hh * 64 + dd)) * PP + p] = vL[lp * 66 + dd];
    }
}

// ---------------------------------------------------------------------------
extern "C" void kernel_launch(void* const* d_in, const int* in_sizes, int n_in,
                              void* d_out, int out_size, void* d_ws, size_t ws_size,
                              hipStream_t stream)
{
    const float* x0     = (const float*)d_in[0];
    const float* dw0_w  = (const float*)d_in[1];
    const float* dw0_s  = (const float*)d_in[2];
    const float* dw0_b  = (const float*)d_in[3];
    const float* dw1_w  = (const float*)d_in[4];
    const float* dw1_s  = (const float*)d_in[5];
    const float* dw1_b  = (const float*)d_in[6];
    const float* f0w1   = (const float*)d_in[7];
    const float* f0s1   = (const float*)d_in[8];
    const float* f0b1   = (const float*)d_in[9];
    const float* f0w2   = (const float*)d_in[10];
    const float* f0s2   = (const float*)d_in[11];
    const float* f0b2   = (const float*)d_in[12];
    const float* f1w1   = (const float*)d_in[13];
    const float* f1s1   = (const float*)d_in[14];
    const float* f1b1   = (const float*)d_in[15];
    const float* f1w2   = (const float*)d_in[16];
    const float* f1s2   = (const float*)d_in[17];
    const float* f1b2   = (const float*)d_in[18];
    const float* qkv_w  = (const float*)d_in[19];
    const float* qkv_s  = (const float*)d_in[20];
    const float* qkv_b  = (const float*)d_in[21];
    const float* dws_w  = (const float*)d_in[22];
    const float* dws_s  = (const float*)d_in[23];
    const float* dws_b  = (const float*)d_in[24];
    const float* proj_w = (const float*)d_in[25];
    const float* proj_s = (const float*)d_in[26];
    const float* proj_b = (const float*)d_in[27];
    const float* pos    = (const float*)d_in[28];

    // -------- workspace (aliased; ~155 MB < 181 MB proven available) --------
    // A: X1 fp32 [64][256][784]
    // B: Hb bf16 [64][512][784] | Qb fp32 [64][64][784]   (disjoint in time)
    // C: QKV bf16 [64][384][784] | X2 fp32 [64][256][784] (disjoint in time)
    // Ob bf16 lives in d_out until the final GEMM overwrites d_out with fp32.
    const size_t NXf = (size_t)BB * DIMC * PP;        // 12,845,056 floats
    float* X1    = (float*)d_ws;
    char*  Bbase = (char*)d_ws + NXf * 4;
    bf16*  Hb    = (bf16*)Bbase;
    float* Qb    = (float*)Bbase;
    char*  Cbase = Bbase + (size_t)BB * HIDC * PP * 2;
    bf16*  QKVb  = (bf16*)Cbase;
    float* X2    = (float*)Cbase;
    bf16*  Wc    = (bf16*)(Cbase + NXf * 4);
    bf16*  Ob    = (bf16*)d_out;
    float* outp  = (float*)d_out;

    bf16* Wf0w1 = Wc;                  // [512][256]
    bf16* Wf0w2 = Wf0w1 + 131072;      // [256][512]
    bf16* Wf1w1 = Wf0w2 + 131072;      // [512][256]
    bf16* Wf1w2 = Wf1w1 + 131072;      // [256][512]
    bf16* Wqkv  = Wf1w2 + 131072;      // [384][256]
    bf16* Wproj = Wqkv + 98304;        // [256][256]

    dim3 blk(256);

    // 0) weights fp32 -> bf16
    cvt_f2b<<<512, blk, 0, stream>>>(f0w1, Wf0w1, 131072);
    cvt_f2b<<<512, blk, 0, stream>>>(f0w2, Wf0w2, 131072);
    cvt_f2b<<<512, blk, 0, stream>>>(f1w1, Wf1w1, 131072);
    cvt_f2b<<<512, blk, 0, stream>>>(f1w2, Wf1w2, 131072);
    cvt_f2b<<<384, blk, 0, stream>>>(qkv_w, Wqkv, 98304);
    cvt_f2b<<<256, blk, 0, stream>>>(proj_w, Wproj, 65536);

    // 1) x = x + dw0(x)
    dw3x3_kernel<<<BB * DIMC, blk, 0, stream>>>(x0, dw0_w, dw0_s, dw0_b, X1);

    // 2-3) ffn0
    gemm_mfma<float, bf16, true, false><<<dim3(7, HIDC / 64, BB), blk, 0, stream>>>(
        Wf0w1, X1, f0s1, f0b1, nullptr, Hb, HIDC, DIMC);
    gemm_mfma<bf16, float, false, true><<<dim3(7, DIMC / 64, BB), blk, 0, stream>>>(
        Wf0w2, Hb, f0s2, f0b2, X1, X1, DIMC, HIDC);

    // 4-7) attention (QKV bf16, O bf16)
    gemm_mfma<float, bf16, false, false><<<dim3(7, 384 / 64, BB), blk, 0, stream>>>(
        Wqkv, X1, qkv_s, qkv_b, nullptr, QKVb, 384, DIMC);
    dws5x5_kernel<<<BB * 64, blk, 0, stream>>>(QKVb, dws_w, dws_s, dws_b, Qb);
    attn_kernel<<<dim3(8, NHH, BB), blk, 0, stream>>>(Qb, QKVb, pos, Ob);
    gemm_mfma<bf16, float, false, true><<<dim3(7, DIMC / 64, BB), blk, 0, stream>>>(
        Wproj, Ob, proj_s, proj_b, X1, X1, DIMC, DIMC);

    // 8) x = x + dw1(x)   (QKV dead -> X2)
    dw3x3_kernel<<<BB * DIMC, blk, 0, stream>>>(X1, dw1_w, dw1_s, dw1_b, X2);

    // 9-10) ffn1, final fp32 NCHW to d_out
    gemm_mfma<float, bf16, true, false><<<dim3(7, HIDC / 64, BB), blk, 0, stream>>>(
        Wf1w1, X2, f1s1, f1b1, nullptr, Hb, HIDC, DIMC);
    gemm_mfma<bf16, float, false, true><<<dim3(7, DIMC / 64, BB), blk, 0, stream>>>(
        Wf1w2, Hb, f1s2, f1b2, X2, outp, DIMC, HIDC);
}

// Round 7
// 791.093 us; speedup vs baseline: 2.0175x; 2.0175x over previous
//
#include <hip/hip_runtime.h>
#include <hip/hip_bf16.h>
#include <math.h>

typedef __hip_bfloat16 bf16;
typedef __attribute__((ext_vector_type(8))) short short8;   // 8 x bf16 MFMA frag
typedef __attribute__((ext_vector_type(4))) float floatx4;  // 4 x f32 MFMA acc

// Problem constants: B=64, DIM=256, HID=512, NH=4, KD=16, D=64, 28x28, WH=7
#define BB    64
#define DIMC  256
#define HIDC  512
#define NHH   4
#define HH_   28
#define WW_   28
#define PP    784   // 28*28

__device__ __forceinline__ float toF(float x) { return x; }
__device__ __forceinline__ float toF(bf16 x) { return __bfloat162float(x); }
__device__ __forceinline__ void stV(float* p, float v) { *p = v; }
__device__ __forceinline__ void stV(bf16* p, float v) { *p = __float2bfloat16(v); }

__device__ __forceinline__ unsigned short f2bits(float f) {
    union { bf16 h; unsigned short u; } cv; cv.h = __float2bfloat16(f); return cv.u;
}
__device__ __forceinline__ float bits2f(unsigned short u) {
    union { unsigned int u32; float f; } cv; cv.u32 = ((unsigned int)u) << 16; return cv.f;
}
__device__ __forceinline__ unsigned short ldbits(const float* p) { return f2bits(*p); }
__device__ __forceinline__ unsigned short ldbits(const bf16* p) {
    return *(const unsigned short*)p;
}

// ---------------------------------------------------------------------------
// fp32 -> bf16 weight convert
// ---------------------------------------------------------------------------
__global__ __launch_bounds__(256) void cvt_f2b(
    const float* __restrict__ s, bf16* __restrict__ d, int n)
{
    int i = blockIdx.x * 256 + threadIdx.x;
    if (i < n) d[i] = __float2bfloat16(s[i]);
}

// ---------------------------------------------------------------------------
// Depthwise 3x3 conv + BN + residual (NCHW) — proven (round 3)
// ---------------------------------------------------------------------------
__global__ __launch_bounds__(256) void dw3x3_kernel(
    const float* __restrict__ in, const float* __restrict__ w,
    const float* __restrict__ s, const float* __restrict__ b,
    float* __restrict__ out)
{
    int nc = blockIdx.x;
    int c  = nc & (DIMC - 1);
    const float* ip = in + (size_t)nc * PP;
    float*       op = out + (size_t)nc * PP;
    float w9[9];
#pragma unroll
    for (int i = 0; i < 9; i++) w9[i] = w[c * 9 + i];
    float sc = s[c], bb = b[c];
    for (int p = threadIdx.x; p < PP; p += 256) {
        int h = p / WW_, x = p % WW_;
        float acc = 0.f;
#pragma unroll
        for (int i = 0; i < 3; i++) {
            int hh = h + i - 1;
            if (hh < 0 || hh >= HH_) continue;
#pragma unroll
            for (int j = 0; j < 3; j++) {
                int xx = x + j - 1;
                if (xx < 0 || xx >= WW_) continue;
                acc += w9[i * 3 + j] * ip[hh * WW_ + xx];
            }
        }
        op[p] = ip[p] + acc * sc + bb;
    }
}

// ---------------------------------------------------------------------------
// Per-head depthwise 5x5 + BN on q channels of bf16 QKV (NCHW) -> bf16 Q
// ---------------------------------------------------------------------------
__global__ __launch_bounds__(256) void dws5x5_kernel(
    const bf16* __restrict__ qkv, const float* __restrict__ w,
    const float* __restrict__ s, const float* __restrict__ b,
    bf16* __restrict__ qout)
{
    int blk = blockIdx.x;         // n*64 + hh*16 + kc
    int n = blk >> 6, hk = blk & 63;
    int hh = hk >> 4, kc = hk & 15;
    const bf16* ip = qkv + ((size_t)n * 384 + hh * 96 + kc) * PP;
    bf16*       op = qout + (size_t)blk * PP;
    float w25[25];
#pragma unroll
    for (int i = 0; i < 25; i++) w25[i] = w[hk * 25 + i];
    float sc = s[hk], bb = b[hk];
    for (int p = threadIdx.x; p < PP; p += 256) {
        int h = p / WW_, x = p % WW_;
        float acc = 0.f;
#pragma unroll
        for (int i = 0; i < 5; i++) {
            int h2 = h + i - 2;
            if (h2 < 0 || h2 >= HH_) continue;
#pragma unroll
            for (int j = 0; j < 5; j++) {
                int x2 = x + j - 2;
                if (x2 < 0 || x2 >= WW_) continue;
                acc += w25[i * 5 + j] * toF(ip[h2 * WW_ + x2]);
            }
        }
        op[p] = __float2bfloat16(acc * sc + bb);
    }
}

// ---------------------------------------------------------------------------
// 1x1 conv as bf16 MFMA GEMM (NCHW) — unchanged from round 6 (proven faster).
// Tile 64(co) x 112(p), K-step 32, 4 waves; b128 LDS staging, pitch 40.
// grid (7, M/64, 64)
// ---------------------------------------------------------------------------
template <typename Tin, typename Tout, bool RELU, bool RES>
__global__ __launch_bounds__(256) void gemm_mfma(
    const bf16* __restrict__ Wb,    // [M][K] bf16
    const Tin*  __restrict__ X,     // [64][K][784]
    const float* __restrict__ S, const float* __restrict__ Bb,
    const float* __restrict__ res,  // [64][M][784] fp32 (if RES)
    Tout* __restrict__ out,         // [64][M][784]
    int M, int K)
{
    int n    = blockIdx.z;
    int co0  = blockIdx.y * 64;
    int p0   = blockIdx.x * 112;
    int tid  = threadIdx.x;
    int wv   = tid >> 6;
    int ln   = tid & 63;
    int l15  = ln & 15;
    int quad = ln >> 4;

    __shared__ __align__(16) unsigned short Blds[112 * 40];  // [pp][kk], pitch 40

    floatx4 acc[7];
#pragma unroll
    for (int t = 0; t < 7; t++) acc[t] = (floatx4){0.f, 0.f, 0.f, 0.f};

    const bf16* Arow = Wb + (size_t)(co0 + wv * 16 + l15) * K + quad * 8;
    const Tin*  Xn   = X + (size_t)n * K * PP;

    int pp_a = tid % 112, G_a = tid / 112;          // always < 448
    int idx_b = tid + 256;
    int pp_b = idx_b % 112, G_b = idx_b / 112;      // valid if idx_b < 448

    for (int k0 = 0; k0 < K; k0 += 32) {
        {
            const Tin* src = Xn + (size_t)(k0 + G_a * 8) * PP + p0 + pp_a;
            union { unsigned short v[8]; uint4 q; } pk;
#pragma unroll
            for (int j = 0; j < 8; j++) pk.v[j] = ldbits(src + (size_t)j * PP);
            *(uint4*)&Blds[pp_a * 40 + G_a * 8] = pk.q;
        }
        if (idx_b < 448) {
            const Tin* src = Xn + (size_t)(k0 + G_b * 8) * PP + p0 + pp_b;
            union { unsigned short v[8]; uint4 q; } pk;
#pragma unroll
            for (int j = 0; j < 8; j++) pk.v[j] = ldbits(src + (size_t)j * PP);
            *(uint4*)&Blds[pp_b * 40 + G_b * 8] = pk.q;
        }
        short8 afrag = *(const short8*)(Arow + k0);
        __syncthreads();
#pragma unroll
        for (int t = 0; t < 7; t++) {
            short8 bfrag = *(const short8*)&Blds[(t * 16 + l15) * 40 + quad * 8];
            acc[t] = __builtin_amdgcn_mfma_f32_16x16x32_bf16(afrag, bfrag, acc[t], 0, 0, 0);
        }
        __syncthreads();
    }

    int cobase = co0 + wv * 16 + quad * 4;
    float s4[4], b4[4];
#pragma unroll
    for (int r = 0; r < 4; r++) { s4[r] = S[cobase + r]; b4[r] = Bb[cobase + r]; }

#pragma unroll
    for (int t = 0; t < 7; t++) {
        int p = p0 + t * 16 + l15;
#pragma unroll
        for (int r = 0; r < 4; r++) {
            float y = acc[t][r] * s4[r] + b4[r];
            if (RELU) y = fmaxf(y, 0.f);
            size_t o = ((size_t)n * M + cobase + r) * PP + p;
            if (RES) y += res[o];
            stV(&out[o], y);
        }
    }
}

// ---------------------------------------------------------------------------
// 7x7 window attention. Block per (n, head, window-row, col-pair): grid (8,4,64).
// Covers 2 windows: rows h0..h0+6, cols col0..col0+13 (lp = r*14 + c).
// Loads/S/softmax as round 6 (coalesced, conflict-free). O computed straight
// from LDS — NO per-thread arrays (round 6's vreg[49] spilled at VGPR=256).
// Thread owns (lp, channel-pair): s-row read is pitch-51 (conflict-free),
// v read is one u32 (two channels) from pitch-66 vL (bank stride 1).
// ---------------------------------------------------------------------------
__global__ __launch_bounds__(256) void attn_kernel(
    const bf16*  __restrict__ Q,       // [64][64][784] bf16 (hk = hh*16+kc)
    const bf16*  __restrict__ KV,      // [64][384][784] bf16
    const float* __restrict__ pos,     // [4][49][49]
    bf16* __restrict__ O)              // [64][256][784] bf16 (c = hh*64+d)
{
    int wjp = blockIdx.x & 1, wi = blockIdx.x >> 1;
    int hh  = blockIdx.y, n = blockIdx.z;
    int tid = threadIdx.x;
    int pbase = wi * 7 * 28 + wjp * 14;   // global p = pbase + r*28 + c

    __shared__ unsigned short qL[16 * 98];   // [kc][lp]
    __shared__ unsigned short kL[16 * 98];
    __shared__ unsigned short vL[98 * 66];   // [lp][d] pitch 66 (bank step 1)
    __shared__ float          sL[98 * 51];   // [w*49+qi][ki] pitch 51 (gcd(51,32)=1)

    const unsigned short* KVu = (const unsigned short*)KV;
    const unsigned short* Qu  = (const unsigned short*)Q;

    // ---- load q, k (16 ch x 98 pos, contiguous 14-elem runs) ----
    for (int idx = tid; idx < 1568; idx += 256) {
        int kc = idx / 98, lp = idx % 98;
        int p  = pbase + (lp / 14) * 28 + lp % 14;
        qL[kc * 98 + lp] = Qu[((size_t)(n * 64 + hh * 16 + kc)) * PP + p];
        kL[kc * 98 + lp] = KVu[((size_t)(n * 384 + hh * 96 + 16 + kc)) * PP + p];
    }
    // ---- load v (64 ch x 98 pos) ----
    for (int idx = tid; idx < 6272; idx += 256) {
        int d = idx / 98, lp = idx % 98;
        int p = pbase + (lp / 14) * 28 + lp % 14;
        vL[lp * 66 + d] = KVu[((size_t)(n * 384 + hh * 96 + 32 + d)) * PP + p];
    }
    __syncthreads();

    // ---- S = 0.25*q.k + pos  (2 windows x 49 x 49) ----
    for (int idx = tid; idx < 4802; idx += 256) {
        int w  = idx / 2401;
        int rm = idx - w * 2401;
        int qi = rm / 49, ki = rm - qi * 49;
        int lpq = (qi / 7) * 14 + w * 7 + qi % 7;
        int lpk = (ki / 7) * 14 + w * 7 + ki % 7;
        float acc = 0.f;
#pragma unroll
        for (int kc = 0; kc < 16; kc++)
            acc += bits2f(qL[kc * 98 + lpq]) * bits2f(kL[kc * 98 + lpk]);
        sL[(w * 49 + qi) * 51 + ki] = acc * 0.25f + pos[(hh * 49 + qi) * 49 + ki];
    }
    __syncthreads();

    // ---- softmax (one thread per row; 98 rows) ----
    if (tid < 98) {
        float* row = &sL[tid * 51];
        float m = row[0];
        for (int ki = 1; ki < 49; ki++) m = fmaxf(m, row[ki]);
        float sum = 0.f;
        for (int ki = 0; ki < 49; ki++) {
            float e = __expf(row[ki] - m);
            row[ki] = e;
            sum += e;
        }
        float inv = 1.f / sum;
        for (int ki = 0; ki < 49; ki++) row[ki] *= inv;
    }
    __syncthreads();

    // ---- O = relu(attn @ V): thread = (lp, channel pair d=2*d2, d+1) ----
    unsigned short* Ou = (unsigned short*)O;
    for (int idx = tid; idx < 3136; idx += 256) {
        int d2 = idx / 98, lp = idx % 98;     // d2 in [0,32)
        int r = lp / 14, c = lp % 14;
        int w = c / 7, cc = c - w * 7;
        int qi = r * 7 + cc;
        const float* srow = &sL[(w * 49 + qi) * 51];
        float a0 = 0.f, a1 = 0.f;
#pragma unroll
        for (int ki = 0; ki < 49; ki++) {
            int lpk = (ki / 7) * 14 + w * 7 + ki % 7;
            unsigned int v2 = *(const unsigned int*)&vL[lpk * 66 + d2 * 2];
            float sv = srow[ki];
            a0 += sv * bits2f((unsigned short)(v2 & 0xFFFF));
            a1 += sv * bits2f((unsigned short)(v2 >> 16));
        }
        int p = pbase + r * 28 + c;
        size_t ob = ((size_t)(n * 256 + hh * 64 + d2 * 2)) * PP + p;
        Ou[ob]      = f2bits(fmaxf(a0, 0.f));
        Ou[ob + PP] = f2bits(fmaxf(a1, 0.f));
    }
}

// ---------------------------------------------------------------------------
extern "C" void kernel_launch(void* const* d_in, const int* in_sizes, int n_in,
                              void* d_out, int out_size, void* d_ws, size_t ws_size,
                              hipStream_t stream)
{
    const float* x0     = (const float*)d_in[0];
    const float* dw0_w  = (const float*)d_in[1];
    const float* dw0_s  = (const float*)d_in[2];
    const float* dw0_b  = (const float*)d_in[3];
    const float* dw1_w  = (const float*)d_in[4];
    const float* dw1_s  = (const float*)d_in[5];
    const float* dw1_b  = (const float*)d_in[6];
    const float* f0w1   = (const float*)d_in[7];
    const float* f0s1   = (const float*)d_in[8];
    const float* f0b1   = (const float*)d_in[9];
    const float* f0w2   = (const float*)d_in[10];
    const float* f0s2   = (const float*)d_in[11];
    const float* f0b2   = (const float*)d_in[12];
    const float* f1w1   = (const float*)d_in[13];
    const float* f1s1   = (const float*)d_in[14];
    const float* f1b1   = (const float*)d_in[15];
    const float* f1w2   = (const float*)d_in[16];
    const float* f1s2   = (const float*)d_in[17];
    const float* f1b2   = (const float*)d_in[18];
    const float* qkv_w  = (const float*)d_in[19];
    const float* qkv_s  = (const float*)d_in[20];
    const float* qkv_b  = (const float*)d_in[21];
    const float* dws_w  = (const float*)d_in[22];
    const float* dws_s  = (const float*)d_in[23];
    const float* dws_b  = (const float*)d_in[24];
    const float* proj_w = (const float*)d_in[25];
    const float* proj_s = (const float*)d_in[26];
    const float* proj_b = (const float*)d_in[27];
    const float* pos    = (const float*)d_in[28];

    // -------- workspace (aliased; same scheme as r5/r6, proven) --------
    // A: X1 fp32 [64][256][784]
    // B: Hb bf16 [64][512][784] | Qb bf16 [64][64][784]   (disjoint in time)
    // C: QKV bf16 [64][384][784] | X2 fp32 [64][256][784] (disjoint in time)
    // Ob bf16 lives in d_out until the final GEMM overwrites d_out with fp32.
    const size_t NXf = (size_t)BB * DIMC * PP;        // 12,845,056 floats
    float* X1    = (float*)d_ws;
    char*  Bbase = (char*)d_ws + NXf * 4;
    bf16*  Hb    = (bf16*)Bbase;
    bf16*  Qb    = (bf16*)Bbase;
    char*  Cbase = Bbase + (size_t)BB * HIDC * PP * 2;
    bf16*  QKVb  = (bf16*)Cbase;
    float* X2    = (float*)Cbase;
    bf16*  Wc    = (bf16*)(Cbase + NXf * 4);
    bf16*  Ob    = (bf16*)d_out;
    float* outp  = (float*)d_out;

    bf16* Wf0w1 = Wc;                  // [512][256]
    bf16* Wf0w2 = Wf0w1 + 131072;      // [256][512]
    bf16* Wf1w1 = Wf0w2 + 131072;      // [512][256]
    bf16* Wf1w2 = Wf1w1 + 131072;      // [256][512]
    bf16* Wqkv  = Wf1w2 + 131072;      // [384][256]
    bf16* Wproj = Wqkv + 98304;        // [256][256]

    dim3 blk(256);

    // 0) weights fp32 -> bf16
    cvt_f2b<<<512, blk, 0, stream>>>(f0w1, Wf0w1, 131072);
    cvt_f2b<<<512, blk, 0, stream>>>(f0w2, Wf0w2, 131072);
    cvt_f2b<<<512, blk, 0, stream>>>(f1w1, Wf1w1, 131072);
    cvt_f2b<<<512, blk, 0, stream>>>(f1w2, Wf1w2, 131072);
    cvt_f2b<<<384, blk, 0, stream>>>(qkv_w, Wqkv, 98304);
    cvt_f2b<<<256, blk, 0, stream>>>(proj_w, Wproj, 65536);

    // 1) x = x + dw0(x)
    dw3x3_kernel<<<BB * DIMC, blk, 0, stream>>>(x0, dw0_w, dw0_s, dw0_b, X1);

    // 2-3) ffn0
    gemm_mfma<float, bf16, true, false><<<dim3(7, HIDC / 64, BB), blk, 0, stream>>>(
        Wf0w1, X1, f0s1, f0b1, nullptr, Hb, HIDC, DIMC);
    gemm_mfma<bf16, float, false, true><<<dim3(7, DIMC / 64, BB), blk, 0, stream>>>(
        Wf0w2, Hb, f0s2, f0b2, X1, X1, DIMC, HIDC);

    // 4-7) attention (QKV bf16, Q bf16, O bf16)
    gemm_mfma<float, bf16, false, false><<<dim3(7, 384 / 64, BB), blk, 0, stream>>>(
        Wqkv, X1, qkv_s, qkv_b, nullptr, QKVb, 384, DIMC);
    dws5x5_kernel<<<BB * 64, blk, 0, stream>>>(QKVb, dws_w, dws_s, dws_b, Qb);
    attn_kernel<<<dim3(8, NHH, BB), blk, 0, stream>>>(Qb, QKVb, pos, Ob);
    gemm_mfma<bf16, float, false, true><<<dim3(7, DIMC / 64, BB), blk, 0, stream>>>(
        Wproj, Ob, proj_s, proj_b, X1, X1, DIMC, DIMC);

    // 8) x = x + dw1(x)   (QKV dead -> X2)
    dw3x3_kernel<<<BB * DIMC, blk, 0, stream>>>(X1, dw1_w, dw1_s, dw1_b, X2);

    // 9-10) ffn1, final fp32 NCHW to d_out
    gemm_mfma<float, bf16, true, false><<<dim3(7, HIDC / 64, BB), blk, 0, stream>>>(
        Wf1w1, X2, f1s1, f1b1, nullptr, Hb, HIDC, DIMC);
    gemm_mfma<bf16, float, false, true><<<dim3(7, DIMC / 64, BB), blk, 0, stream>>>(
        Wf1w2, Hb, f1s2, f1b2, X2, outp, DIMC, HIDC);
}